// Round 2
// baseline (2102.968 us; speedup 1.0000x reference)
//
#include <hip/hip_runtime.h>
#include <hip/hip_bf16.h>

#define Bb 2
#define Hh 48
#define Ww 48
#define C 256
#define NH 8
#define HD 32
#define L 2304          // 48*48
#define NROW (Bb*L)     // 4608
#define QT 6            // queries per attention block

// ---------------------------------------------------------------------------
// K1: fused QKV projection + bias + k-scaling + RoPE, writes fp32
//     q_rot, k_rot, v_perm in [b*NH+n][l][d] layout. 4 rows per block.
// ---------------------------------------------------------------------------
__global__ __launch_bounds__(256) void qkv_rope(
    const float* __restrict__ x,
    const float* __restrict__ wq, const float* __restrict__ bq,
    const float* __restrict__ wk, const float* __restrict__ bk,
    const float* __restrict__ wv, const float* __restrict__ bv,
    const float* __restrict__ sinp, const float* __restrict__ cosp,
    float* __restrict__ q_rot, float* __restrict__ k_rot,
    float* __restrict__ v_perm)
{
    __shared__ float xs[4][C];
    const int c = threadIdx.x;
    const int row0 = blockIdx.x * 4;

    #pragma unroll
    for (int r = 0; r < 4; ++r)
        xs[r][c] = x[(size_t)(row0 + r) * C + c];
    __syncthreads();

    float aq[4] = {0,0,0,0}, ak[4] = {0,0,0,0}, av[4] = {0,0,0,0};
    for (int i = 0; i < C; ++i) {
        const float wqv = wq[i * C + c];
        const float wkv = wk[i * C + c];
        const float wvv = wv[i * C + c];
        #pragma unroll
        for (int r = 0; r < 4; ++r) {
            const float xv = xs[r][i];
            aq[r] += xv * wqv;
            ak[r] += xv * wkv;
            av[r] += xv * wvv;
        }
    }

    const float bqv = bq[c];
    const float bkv = bk[c];
    const float bvv = bv[c];
    const int n = c >> 5, d = c & 31;

    #pragma unroll
    for (int r = 0; r < 4; ++r) {
        const int row = row0 + r;
        const int b = row / L, l = row % L;
        const float sn = sinp[l * HD + d];
        const float cs = cosp[l * HD + d];
        const float q = aq[r] + bqv;
        const float k = (ak[r] + bkv) * 0.17677669529663689f; // 32^-0.5
        const float v = av[r] + bvv;
        // partner lane (c^1) for rotation
        const float qp = __shfl_xor(q, 1);
        const float kp = __shfl_xor(k, 1);
        // even d: rot = -x[d+1]; odd d: rot = x[d-1]
        const float rq = (d & 1) ? qp : -qp;
        const float rk = (d & 1) ? kp : -kp;
        const size_t o = (((size_t)(b * NH + n)) * L + l) * HD + d;
        q_rot[o]  = q * cs + rq * sn;
        k_rot[o]  = k * cs + rk * sn;
        v_perm[o] = v;
    }
}

// ---------------------------------------------------------------------------
// K2: 5x5 depthwise conv on v (reads v_perm layout), writes lepe [b][l][c]
// ---------------------------------------------------------------------------
__global__ __launch_bounds__(256) void dwconv(
    const float* __restrict__ v_perm,
    const float* __restrict__ w_dw, const float* __restrict__ b_dw,
    float* __restrict__ lepe)
{
    const int idx = blockIdx.x * 256 + threadIdx.x;
    const int c = idx & (C - 1);
    const int pix = idx >> 8;          // b*L + l
    const int b = pix / L, l = pix % L;
    const int h = l / Ww, w = l % Ww;
    const int n = c >> 5, d = c & 31;

    const float* vb = v_perm + ((size_t)(b * NH + n)) * L * HD + d;
    float acc = b_dw[c];
    #pragma unroll
    for (int ky = 0; ky < 5; ++ky) {
        const int hy = h + ky - 2;
        if (hy < 0 || hy >= Hh) continue;
        #pragma unroll
        for (int kx = 0; kx < 5; ++kx) {
            const int wx = w + kx - 2;
            if (wx < 0 || wx >= Ww) continue;
            acc += vb[(size_t)(hy * Ww + wx) * HD] * w_dw[(ky * 5 + kx) * C + c];
        }
    }
    lepe[(size_t)pix * C + c] = acc;
}

// ---------------------------------------------------------------------------
// K3: attention. One block = (b, n, 6-query tile). Full score row in LDS,
//     two-pass softmax, then PV. Writes attn_out [b][l][c] fp32.
// ---------------------------------------------------------------------------
__global__ __launch_bounds__(256) void attn(
    const float* __restrict__ q_rot, const float* __restrict__ k_rot,
    const float* __restrict__ v_perm, const float* __restrict__ mask,
    float* __restrict__ attn_out)
{
    __shared__ float sc[QT][L];        // 6*2304*4 = 55296 B
    __shared__ float qs[QT][HD];
    __shared__ float rsum[QT];

    const int tid = threadIdx.x;
    const int ntile = L / QT;          // 384
    const int bn = blockIdx.x / ntile; // 0..15
    const int qt = blockIdx.x % ntile;
    const int b = bn >> 3, n = bn & 7;
    const int q0 = qt * QT;

    if (tid < QT * HD)
        qs[tid / HD][tid % HD] =
            q_rot[((size_t)bn * L + q0 + tid / HD) * HD + (tid % HD)];
    __syncthreads();

    const float* kb = k_rot + (size_t)bn * L * HD;
    const float* mb = mask + ((size_t)(n * L + q0)) * L;

    // ---- score pass: K row in registers, 6 dots per m ----
    for (int m = tid; m < L; m += 256) {
        float4 kv[8];
        const float4* kp = (const float4*)(kb + (size_t)m * HD);
        #pragma unroll
        for (int j = 0; j < 8; ++j) kv[j] = kp[j];
        #pragma unroll
        for (int qi = 0; qi < QT; ++qi) {
            const float4* qp = (const float4*)qs[qi];
            float s = 0.f;
            #pragma unroll
            for (int j = 0; j < 8; ++j) {
                const float4 qv = qp[j];
                s += qv.x * kv[j].x + qv.y * kv[j].y +
                     qv.z * kv[j].z + qv.w * kv[j].w;
            }
            s += mb[(size_t)qi * L + m];
            sc[qi][m] = s;
        }
    }
    __syncthreads();

    // ---- softmax per row (wave w handles rows w, w+4) ----
    const int wave = tid >> 6, lane = tid & 63;
    for (int qi = wave; qi < QT; qi += 4) {
        float mx = -1e30f;
        for (int m = lane; m < L; m += 64) mx = fmaxf(mx, sc[qi][m]);
        #pragma unroll
        for (int off = 32; off >= 1; off >>= 1) mx = fmaxf(mx, __shfl_xor(mx, off));
        float sm = 0.f;
        for (int m = lane; m < L; m += 64) {
            const float p = __expf(sc[qi][m] - mx);
            sc[qi][m] = p;
            sm += p;
        }
        #pragma unroll
        for (int off = 32; off >= 1; off >>= 1) sm += __shfl_xor(sm, off);
        if (lane == 0) rsum[qi] = sm;
    }
    __syncthreads();

    // ---- PV: thread (qi, d), 192 active ----
    if (tid < QT * HD) {
        const int qi = tid / HD, d = tid % HD;
        const float* vb = v_perm + (size_t)bn * L * HD + d;
        float acc = 0.f;
        #pragma unroll 4
        for (int m = 0; m < L; ++m)
            acc += sc[qi][m] * vb[(size_t)m * HD];
        const float o = acc / rsum[qi];
        attn_out[((size_t)b * L + q0 + qi) * C + n * HD + d] = o;
    }
}

// ---------------------------------------------------------------------------
// K4: out = (attn_out + lepe) @ wo + bo, fp32 output. 4 rows per block.
// ---------------------------------------------------------------------------
__global__ __launch_bounds__(256) void outproj(
    const float* __restrict__ attn_out, const float* __restrict__ lepe,
    const float* __restrict__ wo, const float* __restrict__ bo,
    float* __restrict__ out)
{
    __shared__ float xs[4][C];
    const int c = threadIdx.x;
    const int row0 = blockIdx.x * 4;

    #pragma unroll
    for (int r = 0; r < 4; ++r) {
        const size_t o = (size_t)(row0 + r) * C + c;
        xs[r][c] = attn_out[o] + lepe[o];
    }
    __syncthreads();

    float acc[4] = {0,0,0,0};
    for (int i = 0; i < C; ++i) {
        const float w = wo[i * C + c];
        #pragma unroll
        for (int r = 0; r < 4; ++r) acc[r] += xs[r][i] * w;
    }
    const float bov = bo[c];
    #pragma unroll
    for (int r = 0; r < 4; ++r)
        out[(size_t)(row0 + r) * C + c] = acc[r] + bov;
}

// ---------------------------------------------------------------------------
extern "C" void kernel_launch(void* const* d_in, const int* in_sizes, int n_in,
                              void* d_out, int out_size, void* d_ws, size_t ws_size,
                              hipStream_t stream)
{
    const float* x    = (const float*)d_in[0];
    const float* sinp = (const float*)d_in[1];
    const float* cosp = (const float*)d_in[2];
    const float* mask = (const float*)d_in[3];
    const float* wq   = (const float*)d_in[4];
    const float* bq   = (const float*)d_in[5];
    const float* wk   = (const float*)d_in[6];
    const float* bk   = (const float*)d_in[7];
    const float* wv   = (const float*)d_in[8];
    const float* bv   = (const float*)d_in[9];
    const float* w_dw = (const float*)d_in[10];
    const float* b_dw = (const float*)d_in[11];
    const float* wo   = (const float*)d_in[12];
    const float* bo   = (const float*)d_in[13];
    float* out = (float*)d_out;

    float* ws = (float*)d_ws;
    const size_t nqkv = (size_t)Bb * NH * L * HD;  // 1179648
    float* q_rot    = ws;
    float* k_rot    = q_rot + nqkv;
    float* v_perm   = k_rot + nqkv;
    float* lepe     = v_perm + nqkv;
    float* attn_out = lepe + (size_t)Bb * L * C;

    qkv_rope<<<NROW / 4, 256, 0, stream>>>(x, wq, bq, wk, bk, wv, bv,
                                           sinp, cosp, q_rot, k_rot, v_perm);
    dwconv<<<(Bb * L * C) / 256, 256, 0, stream>>>(v_perm, w_dw, b_dw, lepe);
    attn<<<(Bb * NH * L) / QT, 256, 0, stream>>>(q_rot, k_rot, v_perm, mask, attn_out);
    outproj<<<NROW / 4, 256, 0, stream>>>(attn_out, lepe, wo, bo, out);
}

// Round 3
// 394.242 us; speedup vs baseline: 5.3342x; 5.3342x over previous
//
#include <hip/hip_runtime.h>
#include <hip/hip_bf16.h>

#define Bb 2
#define Hh 48
#define Ww 48
#define C 256
#define NH 8
#define HD 32
#define L 2304          // 48*48
#define NROW (Bb*L)     // 4608
#define BQ 64           // q rows per block (16 per wave)
#define BM 64           // k/v tile
#define NQT (L/BQ)      // 36

typedef short  bf16x8 __attribute__((ext_vector_type(8)));
typedef float  f32x4  __attribute__((ext_vector_type(4)));

__device__ __forceinline__ unsigned short f2b(float f) {
    union { float f; unsigned int u; } v; v.f = f;
    unsigned int r = v.u + 0x7fff + ((v.u >> 16) & 1);   // RNE
    return (unsigned short)(r >> 16);
}

// ---------------------------------------------------------------------------
// K1: fused QKV projection + bias + k-scaling + RoPE.
//     q,k -> bf16 [bn][l][d]; v -> fp32 [bn][l][d] (dwconv + transpose input)
// ---------------------------------------------------------------------------
__global__ __launch_bounds__(256) void qkv_rope(
    const float* __restrict__ x,
    const float* __restrict__ wq, const float* __restrict__ bq,
    const float* __restrict__ wk, const float* __restrict__ bk,
    const float* __restrict__ wv, const float* __restrict__ bv,
    const float* __restrict__ sinp, const float* __restrict__ cosp,
    unsigned short* __restrict__ q_bf, unsigned short* __restrict__ k_bf,
    float* __restrict__ v_perm)
{
    __shared__ float xs[4][C];
    const int c = threadIdx.x;
    const int row0 = blockIdx.x * 4;

    #pragma unroll
    for (int r = 0; r < 4; ++r)
        xs[r][c] = x[(size_t)(row0 + r) * C + c];
    __syncthreads();

    float aq[4] = {0,0,0,0}, ak[4] = {0,0,0,0}, av[4] = {0,0,0,0};
    for (int i = 0; i < C; ++i) {
        const float wqv = wq[i * C + c];
        const float wkv = wk[i * C + c];
        const float wvv = wv[i * C + c];
        #pragma unroll
        for (int r = 0; r < 4; ++r) {
            const float xv = xs[r][i];
            aq[r] += xv * wqv;
            ak[r] += xv * wkv;
            av[r] += xv * wvv;
        }
    }

    const float bqv = bq[c];
    const float bkv = bk[c];
    const float bvv = bv[c];
    const int n = c >> 5, d = c & 31;

    #pragma unroll
    for (int r = 0; r < 4; ++r) {
        const int row = row0 + r;
        const int b = row / L, l = row % L;
        const float sn = sinp[l * HD + d];
        const float cs = cosp[l * HD + d];
        const float q = aq[r] + bqv;
        const float k = (ak[r] + bkv) * 0.17677669529663689f; // 32^-0.5
        const float v = av[r] + bvv;
        const float qp = __shfl_xor(q, 1);
        const float kp = __shfl_xor(k, 1);
        const float rq = (d & 1) ? qp : -qp;
        const float rk = (d & 1) ? kp : -kp;
        const size_t o = (((size_t)(b * NH + n)) * L + l) * HD + d;
        q_bf[o]   = f2b(q * cs + rq * sn);
        k_bf[o]   = f2b(k * cs + rk * sn);
        v_perm[o] = v;
    }
}

// ---------------------------------------------------------------------------
// K1b: v_perm fp32 [bn][l][32]  ->  vt_bf bf16 [bn][32][l]  (LDS transpose)
// ---------------------------------------------------------------------------
__global__ __launch_bounds__(256) void v_transpose(
    const float* __restrict__ v_perm, unsigned short* __restrict__ vt_bf)
{
    __shared__ float tile[32][33];
    const int t = threadIdx.x;
    const int bn = blockIdx.x / (L / 32);
    const int l0 = (blockIdx.x % (L / 32)) * 32;

    #pragma unroll
    for (int p = 0; p < 4; ++p) {
        const int row = p * 8 + (t >> 5), col = t & 31;
        tile[row][col] = v_perm[((size_t)bn * L + l0 + row) * HD + col];
    }
    __syncthreads();
    #pragma unroll
    for (int p = 0; p < 4; ++p) {
        const int d = p * 8 + (t >> 5), l = t & 31;
        vt_bf[((size_t)bn * HD + d) * L + l0 + l] = f2b(tile[l][d]);
    }
}

// ---------------------------------------------------------------------------
// K2: 5x5 depthwise conv on v, writes lepe [b][l][c]  (unchanged)
// ---------------------------------------------------------------------------
__global__ __launch_bounds__(256) void dwconv(
    const float* __restrict__ v_perm,
    const float* __restrict__ w_dw, const float* __restrict__ b_dw,
    float* __restrict__ lepe)
{
    const int idx = blockIdx.x * 256 + threadIdx.x;
    const int c = idx & (C - 1);
    const int pix = idx >> 8;
    const int b = pix / L, l = pix % L;
    const int h = l / Ww, w = l % Ww;
    const int n = c >> 5, d = c & 31;

    const float* vb = v_perm + ((size_t)(b * NH + n)) * L * HD + d;
    float acc = b_dw[c];
    #pragma unroll
    for (int ky = 0; ky < 5; ++ky) {
        const int hy = h + ky - 2;
        if (hy < 0 || hy >= Hh) continue;
        #pragma unroll
        for (int kx = 0; kx < 5; ++kx) {
            const int wx = w + kx - 2;
            if (wx < 0 || wx >= Ww) continue;
            acc += vb[(size_t)(hy * Ww + wx) * HD] * w_dw[(ky * 5 + kx) * C + c];
        }
    }
    lepe[(size_t)pix * C + c] = acc;
}

// ---------------------------------------------------------------------------
// K3: flash MFMA attention. Block = (qt, bn); 4 waves, each a 16-row Q tile.
//     mfma_f32_16x16x32_bf16; C/D: col=lane&15, row=(lane>>4)*4+reg (m89);
//     A: A[m=lane&15][k=quad*8+j] (m120). Online softmax, P via LDS.
// ---------------------------------------------------------------------------
__global__ __launch_bounds__(256) void attn_mfma(
    const unsigned short* __restrict__ q_bf,
    const unsigned short* __restrict__ k_bf,
    const unsigned short* __restrict__ vt_bf,
    const float* __restrict__ mask,
    float* __restrict__ attn_out)
{
    __shared__ __align__(16) unsigned short ks[BM * HD];      // [64][32]
    __shared__ __align__(16) unsigned short vs[HD * BM];      // [32][64] chunk-swizzled
    __shared__ __align__(16) unsigned short ps[4][16 * 72];   // per-wave P, stride 72

    const int tid  = threadIdx.x;
    const int wave = tid >> 6, lane = tid & 63;
    const int quad = lane >> 4, l15 = lane & 15;
    const int bn = blockIdx.x & 15;           // b=0/b=1 same-mask pair 8 apart -> same XCD
    const int qt = blockIdx.x >> 4;
    const int b = bn >> 3, n = bn & 7;
    const int q0w = qt * BQ + wave * 16;

    // Q A-fragment (persistent)
    const bf16x8 qa = *(const bf16x8*)(q_bf + (((size_t)bn * L + q0w + l15) * HD + quad * 8));

    const float* mb = mask + (size_t)n * L * L;
    const unsigned short* kg = k_bf  + (size_t)bn * L * HD;
    const unsigned short* vg = vt_bf + (size_t)bn * HD * L;   // [d][l]

    f32x4 O0 = {0,0,0,0}, O1 = {0,0,0,0};
    float mrow[4] = {-1e30f,-1e30f,-1e30f,-1e30f};
    float lrow[4] = {0,0,0,0};

    for (int m0 = 0; m0 < L; m0 += BM) {
        __syncthreads();                       // prior PV readers done before restage
        // stage K tile (contiguous 4 KB)
        *(uint4*)&ks[tid * 8] = *(const uint4*)(kg + (size_t)m0 * HD + tid * 8);
        // stage Vt tile, chunk-rotated: chunk' = (chunk + d) & 7
        {
            const int d = tid >> 3, seg = tid & 7;
            const int sw = (seg + d) & 7;
            *(uint4*)&vs[d * BM + sw * 8] = *(const uint4*)(vg + (size_t)d * L + m0 + seg * 8);
        }
        __syncthreads();

        // ---- QK^T: 4 n-tiles of 16 ----
        f32x4 S[4];
        const f32x4 z = {0,0,0,0};
        #pragma unroll
        for (int t = 0; t < 4; ++t) {
            const bf16x8 kf = *(const bf16x8*)&ks[(t * 16 + l15) * HD + quad * 8];
            S[t] = __builtin_amdgcn_mfma_f32_16x16x32_bf16(qa, kf, z, 0, 0, 0);
        }
        // ---- + mask (fp32) ----
        const float* mp = mb + (size_t)(q0w + quad * 4) * L + m0 + l15;
        #pragma unroll
        for (int t = 0; t < 4; ++t)
            #pragma unroll
            for (int r = 0; r < 4; ++r)
                S[t][r] += mp[(size_t)r * L + t * 16];

        // ---- online softmax (rows live across the 16 lanes of a quad) ----
        float rmax[4];
        #pragma unroll
        for (int r = 0; r < 4; ++r)
            rmax[r] = fmaxf(fmaxf(S[0][r], S[1][r]), fmaxf(S[2][r], S[3][r]));
        #pragma unroll
        for (int off = 1; off <= 8; off <<= 1)
            #pragma unroll
            for (int r = 0; r < 4; ++r)
                rmax[r] = fmaxf(rmax[r], __shfl_xor(rmax[r], off));

        float alpha[4];
        #pragma unroll
        for (int r = 0; r < 4; ++r) {
            const float mn = fmaxf(mrow[r], rmax[r]);
            alpha[r] = __expf(mrow[r] - mn);
            mrow[r] = mn;
        }
        float rs[4] = {0,0,0,0};
        #pragma unroll
        for (int t = 0; t < 4; ++t)
            #pragma unroll
            for (int r = 0; r < 4; ++r) {
                const float p = __expf(S[t][r] - mrow[r]);
                S[t][r] = p;
                rs[r] += p;
            }
        #pragma unroll
        for (int off = 1; off <= 8; off <<= 1)
            #pragma unroll
            for (int r = 0; r < 4; ++r)
                rs[r] += __shfl_xor(rs[r], off);
        #pragma unroll
        for (int r = 0; r < 4; ++r) {
            lrow[r] = lrow[r] * alpha[r] + rs[r];
            O0[r] *= alpha[r];
            O1[r] *= alpha[r];
        }

        // ---- P -> per-wave LDS (C-layout -> A-layout transform) ----
        unsigned short* pw = &ps[wave][0];
        #pragma unroll
        for (int t = 0; t < 4; ++t)
            #pragma unroll
            for (int r = 0; r < 4; ++r)
                pw[(quad * 4 + r) * 72 + t * 16 + l15] = f2b(S[t][r]);
        __syncthreads();   // conservative: order LDS write->read

        // ---- PV: O += P V, k split in two 32-chunks ----
        #pragma unroll
        for (int kh = 0; kh < 2; ++kh) {
            const bf16x8 pa = *(const bf16x8*)&pw[l15 * 72 + kh * 32 + quad * 8];
            {   // d-tile 0
                const int row = l15, sw = ((kh * 4 + quad) + row) & 7;
                const bf16x8 vb = *(const bf16x8*)&vs[row * BM + sw * 8];
                O0 = __builtin_amdgcn_mfma_f32_16x16x32_bf16(pa, vb, O0, 0, 0, 0);
            }
            {   // d-tile 1
                const int row = 16 + l15, sw = ((kh * 4 + quad) + row) & 7;
                const bf16x8 vb = *(const bf16x8*)&vs[row * BM + sw * 8];
                O1 = __builtin_amdgcn_mfma_f32_16x16x32_bf16(pa, vb, O1, 0, 0, 0);
            }
        }
    }

    // ---- epilogue: normalize, write fp32 [b][l][c] ----
    #pragma unroll
    for (int r = 0; r < 4; ++r) {
        const float inv = 1.0f / lrow[r];
        const size_t row = (size_t)b * L + q0w + quad * 4 + r;
        attn_out[row * C + n * HD + l15]      = O0[r] * inv;
        attn_out[row * C + n * HD + 16 + l15] = O1[r] * inv;
    }
}

// ---------------------------------------------------------------------------
// K4: out = (attn_out + lepe) @ wo + bo  (unchanged)
// ---------------------------------------------------------------------------
__global__ __launch_bounds__(256) void outproj(
    const float* __restrict__ attn_out, const float* __restrict__ lepe,
    const float* __restrict__ wo, const float* __restrict__ bo,
    float* __restrict__ out)
{
    __shared__ float xs[4][C];
    const int c = threadIdx.x;
    const int row0 = blockIdx.x * 4;

    #pragma unroll
    for (int r = 0; r < 4; ++r) {
        const size_t o = (size_t)(row0 + r) * C + c;
        xs[r][c] = attn_out[o] + lepe[o];
    }
    __syncthreads();

    float acc[4] = {0,0,0,0};
    for (int i = 0; i < C; ++i) {
        const float w = wo[i * C + c];
        #pragma unroll
        for (int r = 0; r < 4; ++r) acc[r] += xs[r][i] * w;
    }
    const float bov = bo[c];
    #pragma unroll
    for (int r = 0; r < 4; ++r)
        out[(size_t)(row0 + r) * C + c] = acc[r] + bov;
}

// ---------------------------------------------------------------------------
extern "C" void kernel_launch(void* const* d_in, const int* in_sizes, int n_in,
                              void* d_out, int out_size, void* d_ws, size_t ws_size,
                              hipStream_t stream)
{
    const float* x    = (const float*)d_in[0];
    const float* sinp = (const float*)d_in[1];
    const float* cosp = (const float*)d_in[2];
    const float* mask = (const float*)d_in[3];
    const float* wq   = (const float*)d_in[4];
    const float* bq   = (const float*)d_in[5];
    const float* wk   = (const float*)d_in[6];
    const float* bk   = (const float*)d_in[7];
    const float* wv   = (const float*)d_in[8];
    const float* bv   = (const float*)d_in[9];
    const float* w_dw = (const float*)d_in[10];
    const float* b_dw = (const float*)d_in[11];
    const float* wo   = (const float*)d_in[12];
    const float* bo   = (const float*)d_in[13];
    float* out = (float*)d_out;

    float* ws = (float*)d_ws;
    const size_t nqkv = (size_t)Bb * NH * L * HD;   // 1179648
    float* v_perm   = ws;                            // nqkv fp32
    float* lepe     = v_perm + nqkv;                 // NROW*C fp32
    float* attn_out = lepe + (size_t)NROW * C;       // NROW*C fp32
    unsigned short* q_bf  = (unsigned short*)(attn_out + (size_t)NROW * C);
    unsigned short* k_bf  = q_bf + nqkv;
    unsigned short* vt_bf = k_bf + nqkv;

    qkv_rope<<<NROW / 4, 256, 0, stream>>>(x, wq, bq, wk, bk, wv, bv,
                                           sinp, cosp, q_bf, k_bf, v_perm);
    v_transpose<<<Bb * NH * (L / 32), 256, 0, stream>>>(v_perm, vt_bf);
    dwconv<<<(Bb * L * C) / 256, 256, 0, stream>>>(v_perm, w_dw, b_dw, lepe);
    attn_mfma<<<16 * NQT, 256, 0, stream>>>(q_bf, k_bf, vt_bf, mask, attn_out);
    outproj<<<NROW / 4, 256, 0, stream>>>(attn_out, lepe, wo, bo, out);
}